// Round 1
// baseline (195.740 us; speedup 1.0000x reference)
//
#include <hip/hip_runtime.h>
#include <stdint.h>

#define BATCH 128
#define PRI   8732
#define NCLS  21
#define NPR   3
#define TOTAL (BATCH * PRI)            // 1,117,696 (divisible by 256)
#define NBLK  (TOTAL / 256)            // 4366

// ws layout (no memset needed - every slot written unconditionally each launch):
//   [0, KB)        uint32 keys[TOTAL]  monotone-mapped bg_loss; 0 for positives
//   [KB, +17464)   float pm[NBLK]      per-block mask-sum partials
//   [.., +17464)   float pp[NBLK]      per-block pos-loss partials
//   [.., +17464)   float pr[NBLK]      per-block reg-loss partials
//   [.., +1024)    double neg[BATCH]   per-row hard-negative loss sums
//   [.., +4)       uint32 counter      last-block-done arrival counter (k_main zeroes)

typedef const __attribute__((address_space(1))) void gv_t;
typedef __attribute__((address_space(3))) void lv_t;

// ---------------------------------------------------------------------------
// k_main: one 256-anchor chunk per block, staged via async global_load_lds
// (width 16, direct HBM->LDS, no VGPR round-trip). Latency hiding comes from
// 7 LDS-resident blocks/CU overlapping, not intra-block pipelining.
// Also re-zeroes the arrival counter every launch (ws is poisoned between
// iterations); kernel-boundary release/acquire makes it visible to k_select.
// ---------------------------------------------------------------------------
__global__ __launch_bounds__(256)
void k_main(const float* __restrict__ conf, const float* __restrict__ pred,
            const int* __restrict__ labels, const float* __restrict__ gt,
            const float* __restrict__ mask, uint32_t* __restrict__ keys,
            float* __restrict__ pm, float* __restrict__ pp, float* __restrict__ pr,
            uint32_t* __restrict__ counter)
{
  __shared__ __align__(16) float sconf[256 * NCLS];   // 21504 B -> 7 blocks/CU
  __shared__ float sm_[4], sp_[4], sr_[4];
  const int tid = threadIdx.x;
  const int wv  = tid >> 6;              // wave id (wave-uniform)
  const int ln  = tid & 63;
  if (blockIdx.x == 0 && tid == 0) *counter = 0u;     // re-arm last-block pattern
  const long long base = (long long)blockIdx.x * 256;
  const float4* src4 = (const float4*)(conf + base * NCLS);  // 21504 % 16 == 0 -> aligned

  // Async stage 1344 float4 (256 anchors x 21 floats) directly into LDS.
  // LDS dest is wave-uniform base + lane*16 (contiguous layout required).
  #pragma unroll
  for (int i = 0; i < 5; ++i) {
    __builtin_amdgcn_global_load_lds(
        (gv_t*)(src4 + i * 256 + tid),
        (lv_t*)((float4*)sconf + i * 256 + wv * 64),
        16, 0, 0);
  }
  if (wv == 0) {                          // tail: slots 1280..1343 (wave-uniform branch)
    __builtin_amdgcn_global_load_lds(
        (gv_t*)(src4 + 1280 + ln),
        (lv_t*)((float4*)sconf + 1280),
        16, 0, 0);
  }

  // Independent register loads fly alongside the LDS staging.
  const long long a = base + tid;
  const int   lab = labels[a];
  const float mk  = mask[a];

  __syncthreads();                        // vmcnt drain -> LDS + lab/mk ready

  const float* cv = &sconf[tid * NCLS];   // stride 21: gcd(21,32)=1 -> <=2-way alias (free)
  float m = cv[0];
  #pragma unroll
  for (int c = 1; c < NCLS; ++c) m = fmaxf(m, cv[c]);
  float s = 0.f;
  #pragma unroll
  for (int c = 0; c < NCLS; ++c) s += __expf(cv[c] - m);
  const float lse = m + __logf(s);
  const float bg  = lse - cv[0];          // >= 0 always (lse >= max >= cv[0])
  const bool  pos = lab > 0;

  float accm = mk, accp = 0.f, accr = 0.f;
  if (pos) {
    accp = mk * (lse - cv[lab]);
    const float4 pd = ((const float4*)pred)[a];
    const float4 g  = ((const float4*)gt)[a];
    float sl = 0.f, d, ad;
    d = pd.x - g.x; ad = fabsf(d); sl += (ad < 1.f) ? 0.5f * d * d : ad - 0.5f;
    d = pd.y - g.y; ad = fabsf(d); sl += (ad < 1.f) ? 0.5f * d * d : ad - 0.5f;
    d = pd.z - g.z; ad = fabsf(d); sl += (ad < 1.f) ? 0.5f * d * d : ad - 0.5f;
    d = pd.w - g.w; ad = fabsf(d); sl += (ad < 1.f) ? 0.5f * d * d : ad - 0.5f;
    accr = mk * sl;
  }
  keys[a] = pos ? 0u : (__float_as_uint(bg) | 0x80000000u);  // monotone map; pos -> 0 (-inf)

  // Fused 3-way block reduction; partials to ws (no global atomics).
  #pragma unroll
  for (int o = 32; o > 0; o >>= 1) {
    accm += __shfl_down(accm, o);
    accp += __shfl_down(accp, o);
    accr += __shfl_down(accr, o);
  }
  if (ln == 0) { sm_[wv] = accm; sp_[wv] = accp; sr_[wv] = accr; }
  __syncthreads();
  if (tid == 0) {
    pm[blockIdx.x] = sm_[0] + sm_[1] + sm_[2] + sm_[3];
    pp[blockIdx.x] = sp_[0] + sp_[1] + sp_[2] + sp_[3];
    pr[blockIdx.x] = sr_[0] + sr_[1] + sr_[2] + sr_[3];
  }
}

// ---------------------------------------------------------------------------
// k_select: one block (512 threads) per batch row, keys register-resident.
// Exact k-th-largest key via MSB-first search, 2 bits per round (3 candidate
// thresholds, counts monotone) -> 16 barriers. Tie-exact top-k sum.
// The LAST block to finish (device-scope arrival counter) also performs the
// final partial reduction and writes the two outputs (k_final fused away).
// ---------------------------------------------------------------------------
#define SEL_T 512
#define RPT   18                               // 8732 = 512*17 + 28

__global__ __launch_bounds__(SEL_T)
void k_select(const uint32_t* __restrict__ keys,
              const float* __restrict__ pm, const float* __restrict__ pp,
              const float* __restrict__ pr, double* __restrict__ neg,
              uint32_t* __restrict__ counter, float* __restrict__ out)
{
  __shared__ int    slots[16 * 24 + 8];        // fresh region per round
  __shared__ int    ired[8];
  __shared__ double dred[8];
  __shared__ double fred[4][8];
  __shared__ bool   slast;
  const int tid  = threadIdx.x;
  const int w    = tid >> 6;
  const int lane = tid & 63;
  const uint32_t* row = keys + (size_t)blockIdx.x * PRI;

  uint32_t kr[RPT];
  #pragma unroll
  for (int r = 0; r < 17; ++r) kr[r] = row[tid + 512 * r];
  kr[17] = (tid < 28) ? row[tid + 8704] : 0u;  // pad 0: never >= any test (tests >= 2^31)

  // np = zero-key count (pad zeros excluded by tid<28 guard).
  int zc = 0;
  #pragma unroll
  for (int r = 0; r < 17; ++r) zc += (kr[r] == 0u) ? 1 : 0;
  if (tid < 28) zc += (kr[17] == 0u) ? 1 : 0;
  #pragma unroll
  for (int o = 32; o > 0; o >>= 1) zc += __shfl_down(zc, o);
  if (lane == 0) ired[w] = zc;
  __syncthreads();
  int np = 0;
  #pragma unroll
  for (int i = 0; i < 8; ++i) np += ired[i];   // uniform

  int k = np * NPR;
  const int nneg = PRI - np;
  if (k > nneg) k = nneg;

  double result = 0.0;
  if (k > 0) {                                 // uniform branch
    uint32_t cur = 0x80000000u;                // bit31 provably set: nneg >= k
    #pragma unroll 1
    for (int bit = 30; bit >= 1; bit -= 2) {
      const int rnd = (30 - bit) >> 1;
      const uint32_t tA = cur | (3u << (bit - 1));  // bits 11
      const uint32_t tB = cur | (1u << bit);        // bits 10
      const uint32_t tC = cur | (1u << (bit - 1));  // bits 01
      int cA = 0, cB = 0, cC = 0;
      #pragma unroll
      for (int r = 0; r < RPT; ++r) {
        cA += (int)__popcll(__ballot(kr[r] >= tA));
        cB += (int)__popcll(__ballot(kr[r] >= tB));
        cC += (int)__popcll(__ballot(kr[r] >= tC));
      }
      if (lane == 0) {
        int* sl = &slots[rnd * 24];
        sl[w] = cA; sl[8 + w] = cB; sl[16 + w] = cC;
      }
      __syncthreads();
      int TA = 0, TB = 0, TC = 0;
      const int* sl = &slots[rnd * 24];
      #pragma unroll
      for (int i = 0; i < 8; ++i) { TA += sl[i]; TB += sl[8 + i]; TC += sl[16 + i]; }
      cur = (TA >= k) ? tA : (TB >= k) ? tB : (TC >= k) ? tC : cur;  // largest v: count(>=v)>=k
    }
    {                                          // final bit 0
      const uint32_t t = cur | 1u;
      int c = 0;
      #pragma unroll
      for (int r = 0; r < RPT; ++r) c += (int)__popcll(__ballot(kr[r] >= t));
      if (lane == 0) slots[16 * 24 + w] = c;
      __syncthreads();
      int tot = 0;
      #pragma unroll
      for (int i = 0; i < 8; ++i) tot += slots[16 * 24 + i];
      if (tot >= k) cur = t;                   // cur == exact k-th largest key
    }

    const float thr = __uint_as_float(cur & 0x7fffffffu);
    double ssum = 0.0;
    int g = 0;
    #pragma unroll
    for (int r = 0; r < RPT; ++r) {
      if (kr[r] > cur) { ssum += (double)__uint_as_float(kr[r] & 0x7fffffffu); ++g; }
    }
    #pragma unroll
    for (int o = 32; o > 0; o >>= 1) { ssum += __shfl_down(ssum, o); g += __shfl_down(g, o); }
    if (lane == 0) { dred[w] = ssum; ired[w] = g; }
    __syncthreads();
    if (tid == 0) {
      double tot = 0.0; int gg = 0;
      #pragma unroll
      for (int i = 0; i < 8; ++i) { tot += dred[i]; gg += ired[i]; }
      result = tot + (double)(k - gg) * (double)thr;  // tied copies at threshold
    }
  }

  // --- fused finalization: last block to arrive reduces the partials -------
  if (tid == 0) {
    neg[blockIdx.x] = result;                  // unconditional: ws is poisoned
    __threadfence();                           // release neg[] to device scope
    const uint32_t old = __hip_atomic_fetch_add(counter, 1u, __ATOMIC_ACQ_REL,
                                                __HIP_MEMORY_SCOPE_AGENT);
    slast = (old == (uint32_t)(BATCH - 1));
  }
  __syncthreads();
  if (slast) {
    __threadfence();                           // acquire: invalidate stale cachelines
    double sm = 0.0, sp = 0.0, sr = 0.0, sn = 0.0;
    for (int i = tid; i < NBLK; i += SEL_T) {
      sm += (double)pm[i]; sp += (double)pp[i]; sr += (double)pr[i];
    }
    if (tid < BATCH) sn = neg[tid];            // same deterministic tree as old k_final
    #pragma unroll
    for (int o = 32; o > 0; o >>= 1) {
      sm += __shfl_down(sm, o); sp += __shfl_down(sp, o);
      sr += __shfl_down(sr, o); sn += __shfl_down(sn, o);
    }
    if (lane == 0) { fred[0][w] = sm; fred[1][w] = sp; fred[2][w] = sr; fred[3][w] = sn; }
    __syncthreads();
    if (tid == 0) {
      double m = 0, p = 0, r = 0, n = 0;
      #pragma unroll
      for (int i = 0; i < 8; ++i) {
        m += fred[0][i]; p += fred[1][i]; r += fred[2][i]; n += fred[3][i];
      }
      out[0] = (float)(r / m);                 // regression_loss / all_batch_pos
      out[1] = (float)((p + n) / m);           // confidence_loss / all_batch_pos
    }
  }
}

extern "C" void kernel_launch(void* const* d_in, const int* in_sizes, int n_in,
                              void* d_out, int out_size, void* d_ws, size_t ws_size,
                              hipStream_t stream) {
  const float* conf   = (const float*)d_in[0];
  const float* pred   = (const float*)d_in[1];
  const int*   labels = (const int*)d_in[2];
  const float* gt     = (const float*)d_in[3];
  const float* mask   = (const float*)d_in[4];
  float* out = (float*)d_out;

  char* ws = (char*)d_ws;
  const size_t keys_bytes = (size_t)TOTAL * sizeof(uint32_t);  // 4,470,784 (8-aligned)
  uint32_t* keys = (uint32_t*)ws;
  float*  pm  = (float*)(ws + keys_bytes);
  float*  pp  = pm + NBLK;
  float*  pr  = pp + NBLK;
  double* neg = (double*)(ws + keys_bytes + ((3 * NBLK * sizeof(float) + 7) & ~(size_t)7));
  uint32_t* counter = (uint32_t*)(neg + BATCH);

  k_main<<<NBLK, 256, 0, stream>>>(conf, pred, labels, gt, mask, keys, pm, pp, pr, counter);
  k_select<<<BATCH, SEL_T, 0, stream>>>(keys, pm, pp, pr, neg, counter, out);
}